// Round 3
// baseline (138.154 us; speedup 1.0000x reference)
//
#include <hip/hip_runtime.h>

// KPN per-pixel 5x5 predicted convolution, channels-last fp32.
// out[b,h,w,c] = sum_{i,j} feat[b,h+i-2,w+j-2,c] * kernel[b,h,w,i*5+j] + bias[c]
//
// Round 3: branch-free latency pipeline.
//  - Boundary handling folded into LDS weights (OOB taps stored as 0) ->
//    compute loop has ZERO branches: clamped unconditional loads + FMAs.
//  - Explicit 1-row-lookahead software pipeline over 6 feat rows; full unroll
//    -> loads for row r+1 in flight while row r is consumed (fine vmcnt).
//  - 2 output rows per thread (6 rows x 5 cols = 30 loads / 2 outputs),
//    modest VGPR + __launch_bounds__(256,6) -> >=6 waves/SIMD residency.
//  - Weights in LDS [oh][i][wL][8] (j padded 5->8): b128+b32 reads, 8 cg-lanes
//    broadcast, 8 wL-lanes 2-way bank aliasing (free on gfx950).

#define BB 4
#define HH 256
#define WW 256
#define CC 32
#define KK 5
#define OHR 2    // output rows per thread
#define TW 32    // tile width (pixels)
#define TPB 256

__global__ __launch_bounds__(TPB, 6) void kpn_conv_kernel(
    const float* __restrict__ feat,
    const float* __restrict__ kern,
    const float* __restrict__ bias,
    float* __restrict__ out)
{
    // [oh][i][wL][8]: OOB taps pre-zeroed; slots j=5..7 are unread pad.
    __shared__ float sk[OHR * KK * TW * 8];  // 2560 floats = 10.24 KB

    const int t  = threadIdx.x;
    const int bw = blockIdx.x & 7;            // W/TW = 8
    const int bh = (blockIdx.x >> 3) & 127;   // H/OHR = 128
    const int b  = blockIdx.x >> 10;          // 8*128 = 1024
    const int h0 = bh * OHR;
    const int w0 = bw * TW;

    // ---- Stage weights into LDS, zeroing out-of-image taps. ----
    // Source: 2 rows x 32 pixels x 25 taps = 1600 contiguous-ish floats.
    const float* kb = kern + (size_t)((b * HH + h0) * WW + w0) * (KK * KK);
    #pragma unroll
    for (int it = 0; it < 7; ++it) {
        int idx = t + it * TPB;
        if (idx < OHR * TW * KK * KK) {               // 1600
            int oh  = idx / (TW * KK * KK);           // /800
            int rem = idx - oh * (TW * KK * KK);
            int wl  = rem / (KK * KK);                // /25
            int tap = rem - wl * (KK * KK);
            int i   = tap / KK;
            int j   = tap - i * KK;
            int hh  = h0 + oh + i - (KK / 2);
            int ww  = w0 + wl + j - (KK / 2);
            bool v  = ((unsigned)hh < (unsigned)HH) && ((unsigned)ww < (unsigned)WW);
            float val = kb[oh * (WW * KK * KK) + rem];
            sk[((oh * KK + i) * TW + wl) * 8 + j] = v ? val : 0.0f;
        }
    }
    __syncthreads();

    const int cg = (t & 7) * 4;   // channel group
    const int wL = t >> 3;        // 0..31
    const int w  = w0 + wL;

    const float4 bz = *(const float4*)(bias + cg);
    float4 acc[OHR];
    #pragma unroll
    for (int oh = 0; oh < OHR; ++oh) acc[oh] = bz;

    const float* fb = feat + (((size_t)b) << 16) * CC;

    // Clamped column addresses (weights already zero OOB taps).
    int wc[KK];
    #pragma unroll
    for (int j = 0; j < KK; ++j) wc[j] = min(max(w + j - (KK / 2), 0), WW - 1);

    // ---- Software-pipelined row loop: 6 feat rows, 1-row lookahead. ----
    float4 cur[KK], nxt[KK];
    {
        const int hh = min(max(h0 - (KK / 2), 0), HH - 1);
        const float* rp = fb + (((size_t)hh) << 13);  // hh * 256 * 32
        #pragma unroll
        for (int j = 0; j < KK; ++j)
            cur[j] = *(const float4*)(rp + (wc[j] << 5) + cg);
    }

    #pragma unroll
    for (int r = 0; r < OHR + KK - 1; ++r) {          // 6 rows
        if (r < OHR + KK - 2) {                       // compile-time
            const int hh = min(max(h0 + r + 1 - (KK / 2), 0), HH - 1);
            const float* rp = fb + (((size_t)hh) << 13);
            #pragma unroll
            for (int j = 0; j < KK; ++j)
                nxt[j] = *(const float4*)(rp + (wc[j] << 5) + cg);
        }
        #pragma unroll
        for (int oh = 0; oh < OHR; ++oh) {
            const int i = r - oh;                     // kernel row
            if (i >= 0 && i < KK) {                   // compile-time
                const float* wp = sk + ((oh * KK + i) * TW + wL) * 8;
                const float4 w4 = *(const float4*)wp; // taps j=0..3
                const float  w5 = wp[4];              // tap j=4
                acc[oh].x += cur[0].x * w4.x + cur[1].x * w4.y + cur[2].x * w4.z
                           + cur[3].x * w4.w + cur[4].x * w5;
                acc[oh].y += cur[0].y * w4.x + cur[1].y * w4.y + cur[2].y * w4.z
                           + cur[3].y * w4.w + cur[4].y * w5;
                acc[oh].z += cur[0].z * w4.x + cur[1].z * w4.y + cur[2].z * w4.z
                           + cur[3].z * w4.w + cur[4].z * w5;
                acc[oh].w += cur[0].w * w4.x + cur[1].w * w4.y + cur[2].w * w4.z
                           + cur[3].w * w4.w + cur[4].w * w5;
            }
        }
        #pragma unroll
        for (int j = 0; j < KK; ++j) cur[j] = nxt[j]; // SSA-renamed (full unroll)
    }

    // ---- Coalesced stores: 2 rows x 1 KiB per wave. ----
    #pragma unroll
    for (int oh = 0; oh < OHR; ++oh) {
        const size_t pix = (size_t)(b * HH + h0 + oh) * WW + w;
        *(float4*)(out + pix * CC + cg) = acc[oh];
    }
}

extern "C" void kernel_launch(void* const* d_in, const int* in_sizes, int n_in,
                              void* d_out, int out_size, void* d_ws, size_t ws_size,
                              hipStream_t stream) {
    const float* feat = (const float*)d_in[0];
    const float* kern = (const float*)d_in[1];
    const float* bias = (const float*)d_in[2];
    float* out = (float*)d_out;

    dim3 grid(BB * (HH / OHR) * (WW / TW));  // 4096 blocks
    dim3 block(TPB);
    kpn_conv_kernel<<<grid, block, 0, stream>>>(feat, kern, bias, out);
}

// Round 4
// 132.694 us; speedup vs baseline: 1.0411x; 1.0411x over previous
//
#include <hip/hip_runtime.h>

// KPN per-pixel 5x5 predicted convolution, channels-last fp32.
// out[b,h,w,c] = sum_{i,j} feat[b,h+i-2,w+j-2,c] * kernel[b,h,w,i*5+j] + bias[c]
//
// Round 4 = Round 2 structure (VH=4, 40 loads / 4 outputs, VGPR ~90, 42 us)
// with exactly one structural change: the row loop is BRANCH-FREE.
//  - Boundary handling folded into LDS weights (OOB taps stored as 0);
//    feat addresses clamped -> every load unconditional -> the scheduler can
//    overlap row r+1 loads with row r FMAs (R2's runtime row-branch fenced
//    this; R3's manual pipeline + launch_bounds(,6) spilled: WRITE 88 MiB).
//  - NO __launch_bounds__ min-wave clamp, NO manual cur/nxt rotation.
//  - Weights in LDS [oh][i][j][wL]: scalar ds_read_b32, 32 wL-lanes hit 32
//    distinct banks, 8 cg-lanes broadcast -> zero bank conflicts.

#define BB 4
#define HH 256
#define WW 256
#define CC 32
#define KK 5
#define VH 4     // output rows per thread
#define TW 32    // tile width (pixels)
#define TPB 256

__global__ void kpn_conv_kernel(
    const float* __restrict__ feat,
    const float* __restrict__ kern,
    const float* __restrict__ bias,
    float* __restrict__ out)
{
    // [oh][i][j][wL], OOB taps pre-zeroed. 4*5*5*32 = 3200 floats = 12.8 KB.
    __shared__ float sk[VH * KK * KK * TW];

    const int t  = threadIdx.x;
    const int bw = blockIdx.x & 7;           // W/TW = 8
    const int bh = (blockIdx.x >> 3) & 63;   // H/VH = 64
    const int b  = blockIdx.x >> 9;          // B = 4
    const int h0 = bh * VH;
    const int w0 = bw * TW;

    // ---- Stage weights into LDS (transposed, OOB-zeroed). ----
    // kern chunk for this block: rows oh=0..3, each 32 px x 25 taps.
    const float* kb = kern + (size_t)((b * HH + h0) * WW + w0) * (KK * KK);
    for (int idx = t; idx < VH * TW * KK * KK; idx += TPB) {   // 3200
        int oh  = idx / (TW * KK * KK);            // /800
        int rem = idx - oh * (TW * KK * KK);
        int wl  = rem / (KK * KK);                 // /25
        int tap = rem - wl * (KK * KK);
        int i   = tap / KK;
        int j   = tap - i * KK;
        int hh  = h0 + oh + i - (KK / 2);
        int ww  = w0 + wl + j - (KK / 2);
        bool v  = ((unsigned)hh < (unsigned)HH) && ((unsigned)ww < (unsigned)WW);
        float val = kb[(size_t)oh * WW * (KK * KK) + rem];     // coalesced
        sk[((oh * KK + i) * KK + j) * TW + wl] = v ? val : 0.0f;
    }
    __syncthreads();

    const int cg = (t & 7) * 4;   // channel group
    const int wL = t >> 3;        // 0..31
    const int w  = w0 + wL;

    const float4 bz = *(const float4*)(bias + cg);
    float4 acc[VH];
    #pragma unroll
    for (int oh = 0; oh < VH; ++oh) acc[oh] = bz;

    const float* fb = feat + (((size_t)b) << 16) * CC;

    // Clamped column addresses (weights already zero the OOB taps).
    int wc[KK];
    #pragma unroll
    for (int j = 0; j < KK; ++j) wc[j] = min(max(w + j - (KK / 2), 0), WW - 1);

    #pragma unroll
    for (int r = 0; r < VH + KK - 1; ++r) {            // 8 feat rows, no branch
        const int hh = min(max(h0 + r - (KK / 2), 0), HH - 1);
        const float* rp = fb + (((size_t)hh) << 13);   // hh * 256 * 32

        float4 f[KK];
        #pragma unroll
        for (int j = 0; j < KK; ++j)
            f[j] = *(const float4*)(rp + (wc[j] << 5) + cg);

        #pragma unroll
        for (int oh = 0; oh < VH; ++oh) {
            const int i = r - oh;                      // kernel row
            if (i >= 0 && i < KK) {                    // compile-time after unroll
                const float* wp = sk + ((oh * KK + i) * KK) * TW + wL;
                #pragma unroll
                for (int j = 0; j < KK; ++j) {
                    const float wg = wp[j * TW];       // ds_read_b32, no conflict
                    acc[oh].x += f[j].x * wg;
                    acc[oh].y += f[j].y * wg;
                    acc[oh].z += f[j].z * wg;
                    acc[oh].w += f[j].w * wg;
                }
            }
        }
    }

    // ---- Coalesced stores: 4 rows x 1 KiB per wave. ----
    #pragma unroll
    for (int oh = 0; oh < VH; ++oh) {
        const size_t pix = (size_t)(b * HH + h0 + oh) * WW + w;
        *(float4*)(out + pix * CC + cg) = acc[oh];
    }
}

extern "C" void kernel_launch(void* const* d_in, const int* in_sizes, int n_in,
                              void* d_out, int out_size, void* d_ws, size_t ws_size,
                              hipStream_t stream) {
    const float* feat = (const float*)d_in[0];
    const float* kern = (const float*)d_in[1];
    const float* bias = (const float*)d_in[2];
    float* out = (float*)d_out;

    dim3 grid(BB * (HH / VH) * (WW / TW));  // 2048 blocks
    dim3 block(TPB);
    kpn_conv_kernel<<<grid, block, 0, stream>>>(feat, kern, bias, out);
}

// Round 5
// 109.788 us; speedup vs baseline: 1.2584x; 1.2086x over previous
//
#include <hip/hip_runtime.h>

// KPN per-pixel 5x5 predicted convolution, channels-last fp32.
// out[b,h,w,c] = sum_{i,j} feat[b,h+i-2,w+j-2,c] * kernel[b,h,w,i*5+j] + bias[c]
//
// Round 5 = Round 4's branch-free structure with the register policy FIXED:
//  - __launch_bounds__(256, 2): 256-VGPR budget. R3 (cap 85) and R4 (default
//    cap 64) both spilled to scratch (WRITE_SIZE 88/57 MiB vs 32 MiB output)
//    because the branch-free unroll wants ~40 float4 loads in flight (~200
//    VGPRs). Trade TLP (2 waves/SIMD) for deep intra-wave MLP.
//  - Weights staged by STRAIGHT CONTIGUOUS COPY into LDS [pix][25] (R2's
//    proven zero-conflict layout; R4's transposed staging wrote stride-128B
//    -> 4.25M bank-conflict cycles). Reads: 8 cg-lanes broadcast, 8 wL-lanes
//    at stride 25 floats -> banks 25*wL%32 all distinct.
//  - Boundary handling: clamped load addresses + v_cndmask zeroing of the
//    f registers (no weight transform, no branches).

#define BB 4
#define HH 256
#define WW 256
#define CC 32
#define KK 5
#define VH 4     // output rows per thread
#define TW 32    // tile width (pixels)
#define TPB 256

__global__ __launch_bounds__(TPB, 2) void kpn_conv_kernel(
    const float* __restrict__ feat,
    const float* __restrict__ kern,
    const float* __restrict__ bias,
    float* __restrict__ out)
{
    // Natural layout [oh][wL][25]; 4*32*25 = 3200 floats = 12.8 KB.
    __shared__ float sk[VH * TW * KK * KK];

    const int t  = threadIdx.x;
    const int bw = blockIdx.x & 7;           // W/TW = 8
    const int bh = (blockIdx.x >> 3) & 63;   // H/VH = 64
    const int b  = blockIdx.x >> 9;          // B = 4
    const int h0 = bh * VH;
    const int w0 = bw * TW;

    // ---- Stage weights: straight contiguous copy, float4 granularity. ----
    // Per output row oh: 32 px * 25 taps = 800 floats contiguous in global.
    {
        const float* kb = kern + (size_t)((b * HH + h0) * WW + w0) * (KK * KK);
        #pragma unroll
        for (int it = 0; it < 4; ++it) {     // 800 float4 total
            int e = t + it * TPB;
            if (e < VH * TW * KK * KK / 4) {
                int oh  = e / 200;           // 200 float4 per oh-row
                int off = (e - oh * 200) * 4;
                *(float4*)(sk + oh * (TW * KK * KK) + off) =
                    *(const float4*)(kb + (size_t)oh * WW * (KK * KK) + off);
            }
        }
    }
    __syncthreads();

    const int cg = (t & 7) * 4;   // channel group
    const int wL = t >> 3;        // 0..31
    const int w  = w0 + wL;

    const float4 bz = *(const float4*)(bias + cg);
    float4 acc[VH];
    #pragma unroll
    for (int oh = 0; oh < VH; ++oh) acc[oh] = bz;

    const float* fb = feat + (((size_t)b) << 16) * CC;

    // Clamped column addresses + per-column validity (edge lanes only).
    int  wc[KK];
    bool wv[KK];
    #pragma unroll
    for (int j = 0; j < KK; ++j) {
        int ww = w + j - (KK / 2);
        wv[j] = (unsigned)ww < (unsigned)WW;
        wc[j] = min(max(ww, 0), WW - 1);
    }

    #pragma unroll
    for (int r = 0; r < VH + KK - 1; ++r) {            // 8 feat rows, no branch
        const int  hraw = h0 + r - (KK / 2);
        const bool hv   = (unsigned)hraw < (unsigned)HH;
        const int  hh   = min(max(hraw, 0), HH - 1);
        const float* rp = fb + (((size_t)hh) << 13);   // hh * 256 * 32

        float4 f[KK];
        #pragma unroll
        for (int j = 0; j < KK; ++j)
            f[j] = *(const float4*)(rp + (wc[j] << 5) + cg);

        #pragma unroll
        for (int j = 0; j < KK; ++j) {
            if (!(hv && wv[j])) {                      // v_cndmask x4, no branch
                f[j].x = 0.f; f[j].y = 0.f; f[j].z = 0.f; f[j].w = 0.f;
            }
        }

        #pragma unroll
        for (int oh = 0; oh < VH; ++oh) {
            const int i = r - oh;                      // kernel row
            if (i >= 0 && i < KK) {                    // compile-time after unroll
                const float* wp = sk + (oh * TW + wL) * (KK * KK) + i * KK;
                #pragma unroll
                for (int j = 0; j < KK; ++j) {
                    const float wg = wp[j];            // ds_read_b32, 0 conflicts
                    acc[oh].x += f[j].x * wg;
                    acc[oh].y += f[j].y * wg;
                    acc[oh].z += f[j].z * wg;
                    acc[oh].w += f[j].w * wg;
                }
            }
        }
    }

    // ---- Coalesced stores: 4 rows x 1 KiB per wave. ----
    #pragma unroll
    for (int oh = 0; oh < VH; ++oh) {
        const size_t pix = (size_t)(b * HH + h0 + oh) * WW + w;
        *(float4*)(out + pix * CC + cg) = acc[oh];
    }
}

extern "C" void kernel_launch(void* const* d_in, const int* in_sizes, int n_in,
                              void* d_out, int out_size, void* d_ws, size_t ws_size,
                              hipStream_t stream) {
    const float* feat = (const float*)d_in[0];
    const float* kern = (const float*)d_in[1];
    const float* bias = (const float*)d_in[2];
    float* out = (float*)d_out;

    dim3 grid(BB * (HH / VH) * (WW / TW));  // 2048 blocks
    dim3 block(TPB);
    kpn_conv_kernel<<<grid, block, 0, stream>>>(feat, kern, bias, out);
}